// Round 8
// baseline (475.067 us; speedup 1.0000x reference)
//
#include <hip/hip_runtime.h>
#include <hip/hip_bf16.h>

// MoE layer: B=2,S=2048,D=1024,F=4096,E=8,K=2. T=4096 tokens.
// R8: 256x256 BK=32 grouped bf16 MFMA GEMM with R4's proven 3-slot ring
// schedule (stage t+2, vmcnt(4), ONE barrier/tile). 8 waves, 96KB LDS,
// 2-bit XOR swizzle. GEMM2 K-split across blockIdx.z (ksplit by ws_size)
// into bf16 partials, summed deterministically in k_combine.

#define T_TOK 4096
#define D_DIM 1024
#define F_DIM 4096
#define E_NUM 8
#define CAP_ROWS 10240         // 8192 + 8*256 padding headroom
#define N_TILES (CAP_ROWS/256) // 40

typedef __attribute__((ext_vector_type(8))) short short8v;
typedef __attribute__((ext_vector_type(8))) unsigned short ushort8v;
typedef __attribute__((ext_vector_type(4))) float f32x4;

static __device__ __forceinline__ unsigned short f2bf(float f){
  union { float f; unsigned u; } v; v.f = f;
  unsigned r = (v.u + 0x7fffu + ((v.u >> 16) & 1u)) >> 16;  // RNE
  return (unsigned short)r;
}
static __device__ __forceinline__ float bf2f(unsigned short s){
  union { unsigned u; float f; } v; v.u = ((unsigned)s) << 16;
  return v.f;
}

static __device__ __forceinline__ void gload16(const void* g, void* l) {
  __builtin_amdgcn_global_load_lds(
      (const __attribute__((address_space(1))) unsigned int*)g,
      (__attribute__((address_space(3))) unsigned int*)l, 16, 0, 0);
}

__global__ __launch_bounds__(256) void k_init(int* counts, int* cursor,
                                              int* rows_token, float* rows_w){
  const int gid = blockIdx.x * 256 + threadIdx.x;
  if (gid < E_NUM) counts[gid] = 0;
  else if (gid < 2*E_NUM) cursor[gid - E_NUM] = 0;
  if (gid < CAP_ROWS) { rows_token[gid] = 0; rows_w[gid] = 0.f; }  // safe pads
}

// one wave per token: fp32 logits -> softmax -> probs + top-2; emits xbf too
__global__ __launch_bounds__(256) void k_router(
    const float* __restrict__ x, const float* __restrict__ Wr,
    const float* __restrict__ br, float* __restrict__ probs_out,
    int* __restrict__ topi, float* __restrict__ topw, int* __restrict__ counts,
    unsigned short* __restrict__ xbf)
{
  const int lane = threadIdx.x & 63;
  const int t = blockIdx.x * 4 + (threadIdx.x >> 6);
  float xv[16];
  #pragma unroll
  for (int i = 0; i < 16; ++i) xv[i] = x[(size_t)t*D_DIM + i*64 + lane];
  #pragma unroll
  for (int i = 0; i < 16; ++i) xbf[(size_t)t*D_DIM + i*64 + lane] = f2bf(xv[i]);
  float pe[E_NUM];
  #pragma unroll
  for (int e = 0; e < E_NUM; ++e) {
    float p = 0.f;
    #pragma unroll
    for (int i = 0; i < 16; ++i) p += xv[i] * Wr[(i*64 + lane)*E_NUM + e];
    #pragma unroll
    for (int off = 32; off >= 1; off >>= 1) p += __shfl_xor(p, off);
    pe[e] = p + br[e];
  }
  float m = pe[0];
  #pragma unroll
  for (int e = 1; e < E_NUM; ++e) m = fmaxf(m, pe[e]);
  float s = 0.f;
  #pragma unroll
  for (int e = 0; e < E_NUM; ++e) { pe[e] = expf(pe[e] - m); s += pe[e]; }
  const float inv = 1.f / s;
  int e1 = 0; float v1 = pe[0];
  #pragma unroll
  for (int e = 1; e < E_NUM; ++e) if (pe[e] > v1) { v1 = pe[e]; e1 = e; }
  int e2 = (e1 == 0) ? 1 : 0; float v2 = pe[e2];
  #pragma unroll
  for (int e = 0; e < E_NUM; ++e) if (e != e1 && pe[e] > v2) { v2 = pe[e]; e2 = e; }
  if (lane == 0) {
    #pragma unroll
    for (int e = 0; e < E_NUM; ++e) probs_out[(size_t)t*E_NUM + e] = pe[e] * inv;
    topi[t*2+0] = e1; topw[t*2+0] = v1 * inv;
    topi[t*2+1] = e2; topw[t*2+1] = v2 * inv;
    atomicAdd(&counts[e1], 1);
    atomicAdd(&counts[e2], 1);
  }
}

// scan: 256-padded per-expert bases + tile->expert map (one block)
__global__ __launch_bounds__(256) void k_scan(
    const int* __restrict__ counts, int* __restrict__ pbase,
    int* __restrict__ tile_e)
{
  __shared__ int base_s[E_NUM + 1];
  const int tid = threadIdx.x;
  if (tid == 0) {
    int base = 0;
    #pragma unroll
    for (int e = 0; e < E_NUM; ++e) {
      base_s[e] = base;
      base += ((counts[e] + 255) >> 8) << 8;
    }
    base_s[E_NUM] = base;
  }
  __syncthreads();
  if (tid <= E_NUM) pbase[tid] = base_s[tid];
  if (tid < N_TILES) {
    const int r0 = tid << 8;
    int e = -1;
    #pragma unroll
    for (int k = 0; k < E_NUM; ++k)
      if (r0 >= base_s[k] && r0 < base_s[k+1]) e = k;
    tile_e[tid] = e;
  }
}

__global__ __launch_bounds__(256) void k_assign(
    const int* __restrict__ topi, const float* __restrict__ topw,
    const int* __restrict__ pbase, int* __restrict__ cursor,
    int* __restrict__ rows_token, float* __restrict__ rows_w,
    int* __restrict__ pair_of)
{
  const int t = blockIdx.x * 256 + threadIdx.x;
  if (t < T_TOK) {
    #pragma unroll
    for (int k = 0; k < 2; ++k) {
      const int e = topi[t*2+k];
      const int slot = atomicAdd(&cursor[e], 1);
      const int pid = pbase[e] + slot;
      rows_token[pid] = t;
      rows_w[pid] = topw[t*2+k];
      pair_of[t*2+k] = pid;
    }
  }
}

// transpose + convert: per expert, in fp32 [R][C] -> out bf16 [C][R]
template<int R, int C>
__global__ __launch_bounds__(256) void k_tcvt(const float* __restrict__ in,
                                              unsigned short* __restrict__ out)
{
  const size_t eo = (size_t)blockIdx.z * R * C;
  const int r0 = blockIdx.y * 64, c0 = blockIdx.x * 64;
  __shared__ unsigned short ls[64][66];
  const int t = threadIdx.x;
  const int rr = t >> 4, cc = (t & 15) * 4;
  #pragma unroll
  for (int p = 0; p < 4; ++p) {
    const float4 v = *(const float4*)&in[eo + (size_t)(r0 + p*16 + rr)*C + c0 + cc];
    ls[p*16+rr][cc+0]=f2bf(v.x); ls[p*16+rr][cc+1]=f2bf(v.y);
    ls[p*16+rr][cc+2]=f2bf(v.z); ls[p*16+rr][cc+3]=f2bf(v.w);
  }
  __syncthreads();
  const int kc = (t & 7) * 8, nn0 = t >> 3;
  #pragma unroll
  for (int p = 0; p < 2; ++p) {
    const int nn = nn0 + p*32;
    ushort8v o;
    #pragma unroll
    for (int j = 0; j < 8; ++j) o[j] = ls[kc + j][nn];
    *(ushort8v*)&out[eo + (size_t)(c0 + nn)*R + r0 + kc] = o;
  }
}

// grouped bf16 MFMA GEMM: BM=256, BN=256, BK=32, 8 waves (2Mx4N, wave 128x64),
// 3-slot LDS ring (96KB), R4 schedule: stage(t+2) -> compute(t) -> vmcnt(4)
// -> barrier. 2-bit XOR chunk swizzle both sides.
// C[r,n] = sum_k A[r,k]*Bt[n,k].
// EPI 1: relu(acc+bias) -> h.   EPI 2: (acc + (z==0)*bias)*rows_w -> ypart[z].
template<bool GATHER, int NDIM, int KFULL, int EPI>
__global__ __launch_bounds__(512, 2) void k_gemm(
    const unsigned short* __restrict__ A,
    const unsigned short* __restrict__ Bt,   // per-expert [NDIM][KFULL] bf16
    const float* __restrict__ bias,          // [E][NDIM]
    const int* __restrict__ tile_e,
    const int* __restrict__ rows_token,
    const float* __restrict__ rows_w,
    unsigned short* __restrict__ outp,
    int nkt, int kch)
{
  // XCD-bijective swizzle, B-panel-major (proven FETCH cut). tot%8==0.
  const int tot = gridDim.x * gridDim.y;
  int flat = blockIdx.x * gridDim.y + blockIdx.y;
  flat = (flat & 7) * (tot >> 3) + (flat >> 3);
  const int bx = flat / gridDim.y;
  const int by = flat % gridDim.y;
  const int e = tile_e[by];
  if (e < 0) return;
  const int rt = by * 256;
  const int ntc = bx * 256;
  const int koff = blockIdx.z * kch;
  // slot: rows 0-255 = A-tile, rows 256-511 = B-tile; 512x32 bf16 = 32KB
  __shared__ __align__(16) unsigned short LB[3][512*32];
  const int tid = threadIdx.x;
  const int lane = tid & 63;
  const int w = tid >> 6;
  // staging: waves 0-3 -> A rows w*64..; waves 4-7 -> B rows (w-4)*64..
  // call = 16 rows x 64B; lane -> row=lane>>2, chunk g=(lane&3)^((lane>>2)&3)
  const int lrow = lane >> 2;
  const int g = (lane & 3) ^ (lrow & 3);
  const unsigned short* gp[4];
  unsigned lbase[4];
  if (w < 4) {
    #pragma unroll
    for (int i = 0; i < 4; ++i) {
      const int rl = w*64 + i*16 + lrow;
      const int rowidx = GATHER ? rows_token[rt + rl] : (rt + rl);
      gp[i] = A + (size_t)rowidx * KFULL + koff + g*8;
      lbase[i] = (unsigned)((w*64 + i*16) * 32);
    }
  } else {
    const unsigned short* Be = Bt + (size_t)e * NDIM * KFULL;
    #pragma unroll
    for (int i = 0; i < 4; ++i) {
      const int rl = (w-4)*64 + i*16 + lrow;
      gp[i] = Be + (size_t)(ntc + rl) * KFULL + koff + g*8;
      lbase[i] = (unsigned)((256 + (w-4)*64 + i*16) * 32);
    }
  }
  const int wr = w >> 2, wc = w & 3;       // 2M x 4N, wave tile 128x64
  const int cl = lane & 15, rgb = lane >> 4;
  const int ch = (rgb ^ (cl & 3)) * 8;     // swizzled 8-elem chunk in row
  f32x4 acc[8][4] = {};

  #define STG(tt, ss)                                  \
    { const int _ko = (tt) * 32;                       \
      gload16(gp[0] + _ko, &LB[ss][lbase[0]]);         \
      gload16(gp[1] + _ko, &LB[ss][lbase[1]]);         \
      gload16(gp[2] + _ko, &LB[ss][lbase[2]]);         \
      gload16(gp[3] + _ko, &LB[ss][lbase[3]]); }

  // prologue: stage tiles 0,1; certify tile 0 (own 4 of tile 1 in flight)
  STG(0, 0)
  STG(1, 1)
  asm volatile("s_waitcnt vmcnt(4)" ::: "memory");
  __builtin_amdgcn_s_barrier();

  int cur = 0;
  for (int t = 0; t < nkt; ++t) {
    const int pb = (cur == 0) ? 2 : (cur - 1);     // (t+2)%3
    if (t + 2 < nkt) STG(t+2, pb)
    const unsigned short* Sb = LB[cur];
    short8v a[8], b[4];
    #pragma unroll
    for (int m = 0; m < 8; ++m)
      a[m] = *(const short8v*)&Sb[(wr*128 + m*16 + cl)*32 + ch];
    #pragma unroll
    for (int n = 0; n < 4; ++n)
      b[n] = *(const short8v*)&Sb[(256 + wc*64 + n*16 + cl)*32 + ch];
    #pragma unroll
    for (int m = 0; m < 8; ++m)
      #pragma unroll
      for (int n = 0; n < 4; ++n)
        acc[m][n] = __builtin_amdgcn_mfma_f32_16x16x32_bf16(a[m], b[n], acc[m][n], 0, 0, 0);
    if (t + 2 < nkt) { asm volatile("s_waitcnt vmcnt(4)" ::: "memory"); }
    else             { asm volatile("s_waitcnt vmcnt(0)" ::: "memory"); }
    __builtin_amdgcn_s_barrier();
    cur = (cur == 2) ? 0 : (cur + 1);
  }
  #undef STG

  // epilogue: C/D layout col = lane&15, row = (lane>>4)*4 + reg  [m89]
  // pack bf16 pairs across lane^1 -> dword stores from even lanes
  unsigned short* op = outp;
  if (EPI == 2) op += (size_t)blockIdx.z * CAP_ROWS * NDIM;
  const bool addb = (EPI == 1) || (blockIdx.z == 0);
  const size_t ebias = (size_t)e * NDIM;
  #pragma unroll
  for (int m = 0; m < 8; ++m) {
    const int row = rt + wr*128 + m*16 + rgb*4;
    float4 rw4 = make_float4(0,0,0,0);
    if (EPI == 2) rw4 = *(const float4*)&rows_w[row];
    #pragma unroll
    for (int n = 0; n < 4; ++n) {
      const int col = ntc + wc*64 + n*16 + cl;
      const float bv = addb ? bias[ebias + col] : 0.f;
      #pragma unroll
      for (int r = 0; r < 4; ++r) {
        float v = acc[m][n][r] + bv;
        if (EPI == 1) v = fmaxf(v, 0.f);
        else          v *= ((const float*)&rw4)[r];
        const unsigned short hb = f2bf(v);
        const unsigned short ob = (unsigned short)__shfl_xor((int)(unsigned)hb, 1);
        if ((lane & 1) == 0) {
          const unsigned pk = (unsigned)hb | ((unsigned)ob << 16);
          *(unsigned*)&op[(size_t)(row + r)*NDIM + col] = pk;
        }
      }
    }
  }
}

// out[t] = sum_k sum_s ypart[s][pair_k(t)]  (fixed order -> deterministic)
__global__ __launch_bounds__(256) void k_combine(
    const unsigned short* __restrict__ yp, const int* __restrict__ pair_of,
    float* __restrict__ out, int ksplit)
{
  const int gid = blockIdx.x * 256 + threadIdx.x;   // T*D/8 threads
  const int t = gid >> 7;
  const int c = (gid & 127) * 8;
  float o[8] = {0,0,0,0,0,0,0,0};
  #pragma unroll
  for (int k = 0; k < 2; ++k) {
    const int p = pair_of[t*2+k];
    for (int s = 0; s < ksplit; ++s) {
      const ushort8v v = *(const ushort8v*)&yp[((size_t)s*CAP_ROWS + p)*D_DIM + c];
      #pragma unroll
      for (int j = 0; j < 8; ++j) o[j] += bf2f(v[j]);
    }
  }
  float4 o0; o0.x=o[0]; o0.y=o[1]; o0.z=o[2]; o0.w=o[3];
  float4 o1; o1.x=o[4]; o1.y=o[5]; o1.z=o[6]; o1.w=o[7];
  *(float4*)&out[(size_t)t*D_DIM + c]     = o0;
  *(float4*)&out[(size_t)t*D_DIM + c + 4] = o1;
}

extern "C" void kernel_launch(void* const* d_in, const int* in_sizes, int n_in,
                              void* d_out, int out_size, void* d_ws, size_t ws_size,
                              hipStream_t stream)
{
  const float* x  = (const float*)d_in[0];
  const float* Wr = (const float*)d_in[1];
  const float* br = (const float*)d_in[2];
  const float* W1 = (const float*)d_in[3];
  const float* b1 = (const float*)d_in[4];
  const float* W2 = (const float*)d_in[5];
  const float* b2 = (const float*)d_in[6];
  (void)in_sizes; (void)n_in; (void)out_size;

  float* out   = (float*)d_out;
  float* probs = out + (size_t)T_TOK * D_DIM;

  char* w = (char*)d_ws;
  size_t off = 0;
  int*   counts     = (int*)(w + off); off += 256;
  int*   cursor     = (int*)(w + off); off += 256;
  int*   pbase      = (int*)(w + off); off += 512;
  int*   tile_e     = (int*)(w + off); off += 3072;
  int*   topi       = (int*)(w + off); off += (size_t)T_TOK*2*4;
  float* topw       = (float*)(w + off); off += (size_t)T_TOK*2*4;
  int*   pair_of    = (int*)(w + off); off += (size_t)T_TOK*2*4;
  int*   rows_token = (int*)(w + off); off += (size_t)CAP_ROWS*4;
  float* rows_w     = (float*)(w + off); off += (size_t)CAP_ROWS*4;
  off = (off + 255) & ~(size_t)255;
  unsigned short* xbf = (unsigned short*)(w + off); off += (size_t)T_TOK*D_DIM*2;
  unsigned short* Wt  = (unsigned short*)(w + off); off += (size_t)E_NUM*D_DIM*F_DIM*2;
  unsigned short* h   = (unsigned short*)(w + off); off += (size_t)CAP_ROWS*F_DIM*2;
  unsigned short* yp  = (unsigned short*)(w + off);
  // choose GEMM2 K-split by available workspace (deterministic per run)
  const size_t ypart_bytes = (size_t)CAP_ROWS * D_DIM * 2;
  int ksplit = 1;
  if (ws_size >= off + 4 * ypart_bytes) ksplit = 4;
  else if (ws_size >= off + 2 * ypart_bytes) ksplit = 2;
  const int kch2 = F_DIM / ksplit;
  const int nkt2 = kch2 / 32;

  k_init<<<(CAP_ROWS + 255) / 256, 256, 0, stream>>>(counts, cursor, rows_token, rows_w);
  k_router<<<T_TOK / 4, 256, 0, stream>>>(x, Wr, br, probs, topi, topw, counts, xbf);
  k_scan<<<1, 256, 0, stream>>>(counts, pbase, tile_e);
  k_assign<<<T_TOK / 256, 256, 0, stream>>>(topi, topw, pbase, cursor,
                                            rows_token, rows_w, pair_of);
  // W1 [E][D][F] -> Wt [E][F][D] bf16
  k_tcvt<D_DIM, F_DIM><<<dim3(F_DIM/64, D_DIM/64, E_NUM), 256, 0, stream>>>(W1, Wt);
  // GEMM1: tiles 256x256, K=1024 (nkt=32)
  k_gemm<true, F_DIM, D_DIM, 1><<<dim3(F_DIM/256, N_TILES, 1), 512, 0, stream>>>(
      xbf, Wt, b1, tile_e, rows_token, rows_w, h, D_DIM/32, D_DIM);
  // W2 [E][F][D] -> Wt [E][D][F] bf16 (overwrites W1t; stream-ordered)
  k_tcvt<F_DIM, D_DIM><<<dim3(D_DIM/64, F_DIM/64, E_NUM), 256, 0, stream>>>(W2, Wt);
  // GEMM2: tiles 256x256, K split into ksplit chunks along blockIdx.z
  k_gemm<false, D_DIM, F_DIM, 2><<<dim3(D_DIM/256, N_TILES, ksplit), 512, 0, stream>>>(
      h, Wt, b2, tile_e, rows_token, rows_w, yp, nkt2, kch2);
  k_combine<<<T_TOK * D_DIM / 8 / 256, 256, 0, stream>>>(yp, pair_of, out, ksplit);
}

// Round 9
// 464.190 us; speedup vs baseline: 1.0234x; 1.0234x over previous
//
#include <hip/hip_runtime.h>
#include <hip/hip_bf16.h>

// MoE layer: B=2,S=2048,D=1024,F=4096,E=8,K=2. T=4096 tokens.
// R9: m201-style 8-phase (4 phases/K-tile) 256x256 BK=64 grouped bf16 GEMM.
// 8 waves (2Mx4N), 2-buffer LDS 128KB, per-phase {ds_read quadrant, stage,
// barrier, lgkmcnt(0), setprio+16 MFMA, barrier}, vmcnt(4) once per K-tile.
// 8-way XOR swizzle (2-way residual = free). GEMM2 K-split unchanged.

#define T_TOK 4096
#define D_DIM 1024
#define F_DIM 4096
#define E_NUM 8
#define CAP_ROWS 10240         // 8192 + 8*256 padding headroom
#define N_TILES (CAP_ROWS/256) // 40

typedef __attribute__((ext_vector_type(8))) short short8v;
typedef __attribute__((ext_vector_type(8))) unsigned short ushort8v;
typedef __attribute__((ext_vector_type(4))) float f32x4;

static __device__ __forceinline__ unsigned short f2bf(float f){
  union { float f; unsigned u; } v; v.f = f;
  unsigned r = (v.u + 0x7fffu + ((v.u >> 16) & 1u)) >> 16;  // RNE
  return (unsigned short)r;
}
static __device__ __forceinline__ float bf2f(unsigned short s){
  union { unsigned u; float f; } v; v.u = ((unsigned)s) << 16;
  return v.f;
}

static __device__ __forceinline__ void gload16(const void* g, void* l) {
  __builtin_amdgcn_global_load_lds(
      (const __attribute__((address_space(1))) unsigned int*)g,
      (__attribute__((address_space(3))) unsigned int*)l, 16, 0, 0);
}

__global__ __launch_bounds__(256) void k_init(int* counts, int* cursor,
                                              int* rows_token, float* rows_w){
  const int gid = blockIdx.x * 256 + threadIdx.x;
  if (gid < E_NUM) counts[gid] = 0;
  else if (gid < 2*E_NUM) cursor[gid - E_NUM] = 0;
  if (gid < CAP_ROWS) { rows_token[gid] = 0; rows_w[gid] = 0.f; }  // safe pads
}

// one wave per token: fp32 logits -> softmax -> probs + top-2; emits xbf too
__global__ __launch_bounds__(256) void k_router(
    const float* __restrict__ x, const float* __restrict__ Wr,
    const float* __restrict__ br, float* __restrict__ probs_out,
    int* __restrict__ topi, float* __restrict__ topw, int* __restrict__ counts,
    unsigned short* __restrict__ xbf)
{
  const int lane = threadIdx.x & 63;
  const int t = blockIdx.x * 4 + (threadIdx.x >> 6);
  float xv[16];
  #pragma unroll
  for (int i = 0; i < 16; ++i) xv[i] = x[(size_t)t*D_DIM + i*64 + lane];
  #pragma unroll
  for (int i = 0; i < 16; ++i) xbf[(size_t)t*D_DIM + i*64 + lane] = f2bf(xv[i]);
  float pe[E_NUM];
  #pragma unroll
  for (int e = 0; e < E_NUM; ++e) {
    float p = 0.f;
    #pragma unroll
    for (int i = 0; i < 16; ++i) p += xv[i] * Wr[(i*64 + lane)*E_NUM + e];
    #pragma unroll
    for (int off = 32; off >= 1; off >>= 1) p += __shfl_xor(p, off);
    pe[e] = p + br[e];
  }
  float m = pe[0];
  #pragma unroll
  for (int e = 1; e < E_NUM; ++e) m = fmaxf(m, pe[e]);
  float s = 0.f;
  #pragma unroll
  for (int e = 0; e < E_NUM; ++e) { pe[e] = expf(pe[e] - m); s += pe[e]; }
  const float inv = 1.f / s;
  int e1 = 0; float v1 = pe[0];
  #pragma unroll
  for (int e = 1; e < E_NUM; ++e) if (pe[e] > v1) { v1 = pe[e]; e1 = e; }
  int e2 = (e1 == 0) ? 1 : 0; float v2 = pe[e2];
  #pragma unroll
  for (int e = 0; e < E_NUM; ++e) if (e != e1 && pe[e] > v2) { v2 = pe[e]; e2 = e; }
  if (lane == 0) {
    #pragma unroll
    for (int e = 0; e < E_NUM; ++e) probs_out[(size_t)t*E_NUM + e] = pe[e] * inv;
    topi[t*2+0] = e1; topw[t*2+0] = v1 * inv;
    topi[t*2+1] = e2; topw[t*2+1] = v2 * inv;
    atomicAdd(&counts[e1], 1);
    atomicAdd(&counts[e2], 1);
  }
}

// scan: 256-padded per-expert bases + tile->expert map (one block)
__global__ __launch_bounds__(256) void k_scan(
    const int* __restrict__ counts, int* __restrict__ pbase,
    int* __restrict__ tile_e)
{
  __shared__ int base_s[E_NUM + 1];
  const int tid = threadIdx.x;
  if (tid == 0) {
    int base = 0;
    #pragma unroll
    for (int e = 0; e < E_NUM; ++e) {
      base_s[e] = base;
      base += ((counts[e] + 255) >> 8) << 8;
    }
    base_s[E_NUM] = base;
  }
  __syncthreads();
  if (tid <= E_NUM) pbase[tid] = base_s[tid];
  if (tid < N_TILES) {
    const int r0 = tid << 8;
    int e = -1;
    #pragma unroll
    for (int k = 0; k < E_NUM; ++k)
      if (r0 >= base_s[k] && r0 < base_s[k+1]) e = k;
    tile_e[tid] = e;
  }
}

__global__ __launch_bounds__(256) void k_assign(
    const int* __restrict__ topi, const float* __restrict__ topw,
    const int* __restrict__ pbase, int* __restrict__ cursor,
    int* __restrict__ rows_token, float* __restrict__ rows_w,
    int* __restrict__ pair_of)
{
  const int t = blockIdx.x * 256 + threadIdx.x;
  if (t < T_TOK) {
    #pragma unroll
    for (int k = 0; k < 2; ++k) {
      const int e = topi[t*2+k];
      const int slot = atomicAdd(&cursor[e], 1);
      const int pid = pbase[e] + slot;
      rows_token[pid] = t;
      rows_w[pid] = topw[t*2+k];
      pair_of[t*2+k] = pid;
    }
  }
}

// transpose + convert: per expert, in fp32 [R][C] -> out bf16 [C][R]
template<int R, int C>
__global__ __launch_bounds__(256) void k_tcvt(const float* __restrict__ in,
                                              unsigned short* __restrict__ out)
{
  const size_t eo = (size_t)blockIdx.z * R * C;
  const int r0 = blockIdx.y * 64, c0 = blockIdx.x * 64;
  __shared__ unsigned short ls[64][66];
  const int t = threadIdx.x;
  const int rr = t >> 4, cc = (t & 15) * 4;
  #pragma unroll
  for (int p = 0; p < 4; ++p) {
    const float4 v = *(const float4*)&in[eo + (size_t)(r0 + p*16 + rr)*C + c0 + cc];
    ls[p*16+rr][cc+0]=f2bf(v.x); ls[p*16+rr][cc+1]=f2bf(v.y);
    ls[p*16+rr][cc+2]=f2bf(v.z); ls[p*16+rr][cc+3]=f2bf(v.w);
  }
  __syncthreads();
  const int kc = (t & 7) * 8, nn0 = t >> 3;
  #pragma unroll
  for (int p = 0; p < 2; ++p) {
    const int nn = nn0 + p*32;
    ushort8v o;
    #pragma unroll
    for (int j = 0; j < 8; ++j) o[j] = ls[kc + j][nn];
    *(ushort8v*)&out[eo + (size_t)(c0 + nn)*R + r0 + kc] = o;
  }
}

// grouped bf16 MFMA GEMM: BM=256, BN=256, BK=64, 8 waves (2Mx4N),
// 2-buffer LDS (128KB), 4 phases/K-tile (m201 template), vmcnt(4)/K-tile.
// C[r,n] = sum_k A[r,k]*Bt[n,k].
// EPI 1: relu(acc+bias) -> h.   EPI 2: (acc + (z==0)*bias)*rows_w -> ypart[z].
template<bool GATHER, int NDIM, int KFULL, int EPI>
__global__ __launch_bounds__(512, 2) void k_gemm(
    const unsigned short* __restrict__ A,
    const unsigned short* __restrict__ Bt,   // per-expert [NDIM][KFULL] bf16
    const float* __restrict__ bias,          // [E][NDIM]
    const int* __restrict__ tile_e,
    const int* __restrict__ rows_token,
    const float* __restrict__ rows_w,
    unsigned short* __restrict__ outp,
    int nkt, int kch)
{
  // XCD-bijective swizzle, B-panel-major (proven FETCH cut). tot%8==0.
  const int tot = gridDim.x * gridDim.y;
  int flat = blockIdx.x * gridDim.y + blockIdx.y;
  flat = (flat & 7) * (tot >> 3) + (flat >> 3);
  const int bx = flat / gridDim.y;
  const int by = flat % gridDim.y;
  const int e = tile_e[by];
  if (e < 0) return;
  const int rt = by * 256;
  const int ntc = bx * 256;
  const int koff = blockIdx.z * kch;
  // buffer: rows 0-255 = A-tile (256x64), rows 256-511 = B-tile. 64KB each.
  __shared__ __align__(16) unsigned short LB[2][512 * 64];
  const int tid = threadIdx.x;
  const int lane = tid & 63;
  const int w = tid >> 6;
  // staging: wave w<4 -> A rows [w*64, w*64+64); w>=4 -> B same. 8 calls/wave
  // per K-tile, each call = 8 rows x 128B (lane -> row=lane>>3, chunk lane&7).
  // LDS dest linear; global chunk pre-swizzled g = (lane&7) ^ (row&7).
  const int lr = lane >> 3;
  const int g  = (lane & 7) ^ lr;
  const unsigned short* gp[8];
  unsigned lbase[8];
  if (w < 4) {
    #pragma unroll
    for (int i = 0; i < 8; ++i) {
      const int rl = w*64 + i*8 + lr;
      const int rowidx = GATHER ? rows_token[rt + rl] : (rt + rl);
      gp[i] = A + (size_t)rowidx * KFULL + koff + g*8;
      lbase[i] = (unsigned)((w*64 + i*8) * 64);
    }
  } else {
    const unsigned short* Be = Bt + (size_t)e * NDIM * KFULL;
    #pragma unroll
    for (int i = 0; i < 8; ++i) {
      const int rl = (w-4)*64 + i*8 + lr;
      gp[i] = Be + (size_t)(ntc + rl) * KFULL + koff + g*8;
      lbase[i] = (unsigned)((256 + (w-4)*64 + i*8) * 64);
    }
  }
  const int wr = w >> 2, wc = w & 3;       // 2M x 4N, wave tile 128x64
  const int cl = lane & 15, rgb = lane >> 4;
  const int sz = cl & 7;                   // read-side XOR (row&7 == cl&7)
  f32x4 acc[8][4] = {};

  #define STG4(tt, bb, c0)                                    \
    { const int _ko = (tt) * 64;                              \
      gload16(gp[c0+0] + _ko, &LB[bb][lbase[c0+0]]);          \
      gload16(gp[c0+1] + _ko, &LB[bb][lbase[c0+1]]);          \
      gload16(gp[c0+2] + _ko, &LB[bb][lbase[c0+2]]);          \
      gload16(gp[c0+3] + _ko, &LB[bb][lbase[c0+3]]); }
  #define LGK0  asm volatile("s_waitcnt lgkmcnt(0)" ::: "memory")
  #define BAR   __builtin_amdgcn_s_barrier()

  // prologue: tile0 fully (8 calls), tile1 first half (4); certify tile0
  STG4(0, 0, 0) STG4(0, 0, 4)
  STG4(1, 1, 0)
  asm volatile("s_waitcnt vmcnt(4)" ::: "memory");
  BAR;

  for (int t = 0; t < nkt; ++t) {
    const int bb = t & 1;
    const unsigned short* Sb = &LB[bb][0];
    short8v a[4][2], b[4][2];
    // ---- P1: read a[0-3]+b[0-1]; stage t+1 second half -> buf bb^1; q1
    #pragma unroll
    for (int m = 0; m < 4; ++m) {
      a[m][0] = *(const short8v*)&Sb[(wr*128 + m*16 + cl)*64 + ((0*4+rgb)^sz)*8];
      a[m][1] = *(const short8v*)&Sb[(wr*128 + m*16 + cl)*64 + ((1*4+rgb)^sz)*8];
    }
    #pragma unroll
    for (int n = 0; n < 2; ++n) {
      b[n][0] = *(const short8v*)&Sb[(256 + wc*64 + n*16 + cl)*64 + ((0*4+rgb)^sz)*8];
      b[n][1] = *(const short8v*)&Sb[(256 + wc*64 + n*16 + cl)*64 + ((1*4+rgb)^sz)*8];
    }
    if (t + 1 < nkt) STG4(t+1, bb^1, 4)
    BAR; LGK0;
    __builtin_amdgcn_s_setprio(1);
    #pragma unroll
    for (int m = 0; m < 4; ++m)
      #pragma unroll
      for (int n = 0; n < 2; ++n) {
        acc[m][n] = __builtin_amdgcn_mfma_f32_16x16x32_bf16(a[m][0], b[n][0], acc[m][n], 0, 0, 0);
        acc[m][n] = __builtin_amdgcn_mfma_f32_16x16x32_bf16(a[m][1], b[n][1], acc[m][n], 0, 0, 0);
      }
    __builtin_amdgcn_s_setprio(0);
    BAR;
    // ---- P2: read b[2-3]; q2
    #pragma unroll
    for (int n = 2; n < 4; ++n) {
      b[n][0] = *(const short8v*)&Sb[(256 + wc*64 + n*16 + cl)*64 + ((0*4+rgb)^sz)*8];
      b[n][1] = *(const short8v*)&Sb[(256 + wc*64 + n*16 + cl)*64 + ((1*4+rgb)^sz)*8];
    }
    BAR; LGK0;
    __builtin_amdgcn_s_setprio(1);
    #pragma unroll
    for (int m = 0; m < 4; ++m)
      #pragma unroll
      for (int n = 2; n < 4; ++n) {
        acc[m][n] = __builtin_amdgcn_mfma_f32_16x16x32_bf16(a[m][0], b[n][0], acc[m][n], 0, 0, 0);
        acc[m][n] = __builtin_amdgcn_mfma_f32_16x16x32_bf16(a[m][1], b[n][1], acc[m][n], 0, 0, 0);
      }
    __builtin_amdgcn_s_setprio(0);
    BAR;
    // ---- P3: read a[4-7] (reuse regs); q3
    #pragma unroll
    for (int m = 0; m < 4; ++m) {
      a[m][0] = *(const short8v*)&Sb[(wr*128 + (m+4)*16 + cl)*64 + ((0*4+rgb)^sz)*8];
      a[m][1] = *(const short8v*)&Sb[(wr*128 + (m+4)*16 + cl)*64 + ((1*4+rgb)^sz)*8];
    }
    BAR; LGK0;
    __builtin_amdgcn_s_setprio(1);
    #pragma unroll
    for (int m = 0; m < 4; ++m)
      #pragma unroll
      for (int n = 0; n < 2; ++n) {
        acc[m+4][n] = __builtin_amdgcn_mfma_f32_16x16x32_bf16(a[m][0], b[n][0], acc[m+4][n], 0, 0, 0);
        acc[m+4][n] = __builtin_amdgcn_mfma_f32_16x16x32_bf16(a[m][1], b[n][1], acc[m+4][n], 0, 0, 0);
      }
    __builtin_amdgcn_s_setprio(0);
    BAR;
    // ---- P4: stage t+2 first half -> buf bb (reads retired at P3); vmcnt; q4
    if (t + 2 < nkt) {
      STG4(t+2, bb, 0)
      asm volatile("s_waitcnt vmcnt(4)" ::: "memory");   // tile t+1 landed
    } else if (t + 1 < nkt) {
      asm volatile("s_waitcnt vmcnt(0)" ::: "memory");
    }
    BAR;
    __builtin_amdgcn_s_setprio(1);
    #pragma unroll
    for (int m = 0; m < 4; ++m)
      #pragma unroll
      for (int n = 2; n < 4; ++n) {
        acc[m+4][n] = __builtin_amdgcn_mfma_f32_16x16x32_bf16(a[m][0], b[n][0], acc[m+4][n], 0, 0, 0);
        acc[m+4][n] = __builtin_amdgcn_mfma_f32_16x16x32_bf16(a[m][1], b[n][1], acc[m+4][n], 0, 0, 0);
      }
    __builtin_amdgcn_s_setprio(0);
    BAR;
  }
  #undef STG4
  #undef LGK0
  #undef BAR

  // epilogue: C/D layout col = lane&15, row = (lane>>4)*4 + reg  [m89]
  // pack bf16 pairs across lane^1 -> dword stores from even lanes
  unsigned short* op = outp;
  if (EPI == 2) op += (size_t)blockIdx.z * CAP_ROWS * NDIM;
  const bool addb = (EPI == 1) || (blockIdx.z == 0);
  const size_t ebias = (size_t)e * NDIM;
  #pragma unroll
  for (int m = 0; m < 8; ++m) {
    const int row = rt + wr*128 + m*16 + rgb*4;
    float4 rw4 = make_float4(0,0,0,0);
    if (EPI == 2) rw4 = *(const float4*)&rows_w[row];
    #pragma unroll
    for (int n = 0; n < 4; ++n) {
      const int col = ntc + wc*64 + n*16 + cl;
      const float bv = addb ? bias[ebias + col] : 0.f;
      #pragma unroll
      for (int r = 0; r < 4; ++r) {
        float v = acc[m][n][r] + bv;
        if (EPI == 1) v = fmaxf(v, 0.f);
        else          v *= ((const float*)&rw4)[r];
        const unsigned short hb = f2bf(v);
        const unsigned short ob = (unsigned short)__shfl_xor((int)(unsigned)hb, 1);
        if ((lane & 1) == 0) {
          const unsigned pk = (unsigned)hb | ((unsigned)ob << 16);
          *(unsigned*)&op[(size_t)(row + r)*NDIM + col] = pk;
        }
      }
    }
  }
}

// out[t] = sum_k sum_s ypart[s][pair_k(t)]  (fixed order -> deterministic)
__global__ __launch_bounds__(256) void k_combine(
    const unsigned short* __restrict__ yp, const int* __restrict__ pair_of,
    float* __restrict__ out, int ksplit)
{
  const int gid = blockIdx.x * 256 + threadIdx.x;   // T*D/8 threads
  const int t = gid >> 7;
  const int c = (gid & 127) * 8;
  float o[8] = {0,0,0,0,0,0,0,0};
  #pragma unroll
  for (int k = 0; k < 2; ++k) {
    const int p = pair_of[t*2+k];
    for (int s = 0; s < ksplit; ++s) {
      const ushort8v v = *(const ushort8v*)&yp[((size_t)s*CAP_ROWS + p)*D_DIM + c];
      #pragma unroll
      for (int j = 0; j < 8; ++j) o[j] += bf2f(v[j]);
    }
  }
  float4 o0; o0.x=o[0]; o0.y=o[1]; o0.z=o[2]; o0.w=o[3];
  float4 o1; o1.x=o[4]; o1.y=o[5]; o1.z=o[6]; o1.w=o[7];
  *(float4*)&out[(size_t)t*D_DIM + c]     = o0;
  *(float4*)&out[(size_t)t*D_DIM + c + 4] = o1;
}

extern "C" void kernel_launch(void* const* d_in, const int* in_sizes, int n_in,
                              void* d_out, int out_size, void* d_ws, size_t ws_size,
                              hipStream_t stream)
{
  const float* x  = (const float*)d_in[0];
  const float* Wr = (const float*)d_in[1];
  const float* br = (const float*)d_in[2];
  const float* W1 = (const float*)d_in[3];
  const float* b1 = (const float*)d_in[4];
  const float* W2 = (const float*)d_in[5];
  const float* b2 = (const float*)d_in[6];
  (void)in_sizes; (void)n_in; (void)out_size;

  float* out   = (float*)d_out;
  float* probs = out + (size_t)T_TOK * D_DIM;

  char* w = (char*)d_ws;
  size_t off = 0;
  int*   counts     = (int*)(w + off); off += 256;
  int*   cursor     = (int*)(w + off); off += 256;
  int*   pbase      = (int*)(w + off); off += 512;
  int*   tile_e     = (int*)(w + off); off += 3072;
  int*   topi       = (int*)(w + off); off += (size_t)T_TOK*2*4;
  float* topw       = (float*)(w + off); off += (size_t)T_TOK*2*4;
  int*   pair_of    = (int*)(w + off); off += (size_t)T_TOK*2*4;
  int*   rows_token = (int*)(w + off); off += (size_t)CAP_ROWS*4;
  float* rows_w     = (float*)(w + off); off += (size_t)CAP_ROWS*4;
  off = (off + 255) & ~(size_t)255;
  unsigned short* xbf = (unsigned short*)(w + off); off += (size_t)T_TOK*D_DIM*2;
  unsigned short* Wt  = (unsigned short*)(w + off); off += (size_t)E_NUM*D_DIM*F_DIM*2;
  unsigned short* h   = (unsigned short*)(w + off); off += (size_t)CAP_ROWS*F_DIM*2;
  unsigned short* yp  = (unsigned short*)(w + off);
  // choose GEMM2 K-split by available workspace (deterministic per run)
  const size_t ypart_bytes = (size_t)CAP_ROWS * D_DIM * 2;
  int ksplit = 1;
  if (ws_size >= off + 4 * ypart_bytes) ksplit = 4;
  else if (ws_size >= off + 2 * ypart_bytes) ksplit = 2;
  const int kch2 = F_DIM / ksplit;
  const int nkt2 = kch2 / 64;

  k_init<<<(CAP_ROWS + 255) / 256, 256, 0, stream>>>(counts, cursor, rows_token, rows_w);
  k_router<<<T_TOK / 4, 256, 0, stream>>>(x, Wr, br, probs, topi, topw, counts, xbf);
  k_scan<<<1, 256, 0, stream>>>(counts, pbase, tile_e);
  k_assign<<<T_TOK / 256, 256, 0, stream>>>(topi, topw, pbase, cursor,
                                            rows_token, rows_w, pair_of);
  // W1 [E][D][F] -> Wt [E][F][D] bf16
  k_tcvt<D_DIM, F_DIM><<<dim3(F_DIM/64, D_DIM/64, E_NUM), 256, 0, stream>>>(W1, Wt);
  // GEMM1: tiles 256x256, K=1024 (nkt=16)
  k_gemm<true, F_DIM, D_DIM, 1><<<dim3(F_DIM/256, N_TILES, 1), 512, 0, stream>>>(
      xbf, Wt, b1, tile_e, rows_token, rows_w, h, D_DIM/64, D_DIM);
  // W2 [E][F][D] -> Wt [E][D][F] bf16 (overwrites W1t; stream-ordered)
  k_tcvt<F_DIM, D_DIM><<<dim3(D_DIM/64, F_DIM/64, E_NUM), 256, 0, stream>>>(W2, Wt);
  // GEMM2: tiles 256x256, K split into ksplit chunks along blockIdx.z
  k_gemm<false, D_DIM, F_DIM, 2><<<dim3(D_DIM/256, N_TILES, ksplit), 512, 0, stream>>>(
      h, Wt, b2, tile_e, rows_token, rows_w, yp, nkt2, kch2);
  k_combine<<<T_TOK * D_DIM / 8 / 256, 256, 0, stream>>>(yp, pair_of, out, ksplit);
}

// Round 10
// 461.129 us; speedup vs baseline: 1.0302x; 1.0066x over previous
//
#include <hip/hip_runtime.h>
#include <hip/hip_bf16.h>

// MoE layer: B=2,S=2048,D=1024,F=4096,E=8,K=2. T=4096 tokens.
// R10: R9's 8-phase 256x256 BK=64 GEMM + XCD 2D-locality remap:
// each XCD owns all B-panels x 5 contiguous row-tiles (A set 2.5MB L2-resident,
// B-panel reused x5 consecutively). t+1 staging spread 2+2 over P1/P2.

#define T_TOK 4096
#define D_DIM 1024
#define F_DIM 4096
#define E_NUM 8
#define CAP_ROWS 10240         // 8192 + 8*256 padding headroom
#define N_TILES (CAP_ROWS/256) // 40
#define BYG (N_TILES/8)        // 5 row-tiles per XCD

typedef __attribute__((ext_vector_type(8))) short short8v;
typedef __attribute__((ext_vector_type(8))) unsigned short ushort8v;
typedef __attribute__((ext_vector_type(4))) float f32x4;

static __device__ __forceinline__ unsigned short f2bf(float f){
  union { float f; unsigned u; } v; v.f = f;
  unsigned r = (v.u + 0x7fffu + ((v.u >> 16) & 1u)) >> 16;  // RNE
  return (unsigned short)r;
}
static __device__ __forceinline__ float bf2f(unsigned short s){
  union { unsigned u; float f; } v; v.u = ((unsigned)s) << 16;
  return v.f;
}

static __device__ __forceinline__ void gload16(const void* g, void* l) {
  __builtin_amdgcn_global_load_lds(
      (const __attribute__((address_space(1))) unsigned int*)g,
      (__attribute__((address_space(3))) unsigned int*)l, 16, 0, 0);
}

__global__ __launch_bounds__(256) void k_init(int* counts, int* cursor,
                                              int* rows_token, float* rows_w){
  const int gid = blockIdx.x * 256 + threadIdx.x;
  if (gid < E_NUM) counts[gid] = 0;
  else if (gid < 2*E_NUM) cursor[gid - E_NUM] = 0;
  if (gid < CAP_ROWS) { rows_token[gid] = 0; rows_w[gid] = 0.f; }  // safe pads
}

// one wave per token: fp32 logits -> softmax -> probs + top-2; emits xbf too
__global__ __launch_bounds__(256) void k_router(
    const float* __restrict__ x, const float* __restrict__ Wr,
    const float* __restrict__ br, float* __restrict__ probs_out,
    int* __restrict__ topi, float* __restrict__ topw, int* __restrict__ counts,
    unsigned short* __restrict__ xbf)
{
  const int lane = threadIdx.x & 63;
  const int t = blockIdx.x * 4 + (threadIdx.x >> 6);
  float xv[16];
  #pragma unroll
  for (int i = 0; i < 16; ++i) xv[i] = x[(size_t)t*D_DIM + i*64 + lane];
  #pragma unroll
  for (int i = 0; i < 16; ++i) xbf[(size_t)t*D_DIM + i*64 + lane] = f2bf(xv[i]);
  float pe[E_NUM];
  #pragma unroll
  for (int e = 0; e < E_NUM; ++e) {
    float p = 0.f;
    #pragma unroll
    for (int i = 0; i < 16; ++i) p += xv[i] * Wr[(i*64 + lane)*E_NUM + e];
    #pragma unroll
    for (int off = 32; off >= 1; off >>= 1) p += __shfl_xor(p, off);
    pe[e] = p + br[e];
  }
  float m = pe[0];
  #pragma unroll
  for (int e = 1; e < E_NUM; ++e) m = fmaxf(m, pe[e]);
  float s = 0.f;
  #pragma unroll
  for (int e = 0; e < E_NUM; ++e) { pe[e] = expf(pe[e] - m); s += pe[e]; }
  const float inv = 1.f / s;
  int e1 = 0; float v1 = pe[0];
  #pragma unroll
  for (int e = 1; e < E_NUM; ++e) if (pe[e] > v1) { v1 = pe[e]; e1 = e; }
  int e2 = (e1 == 0) ? 1 : 0; float v2 = pe[e2];
  #pragma unroll
  for (int e = 0; e < E_NUM; ++e) if (e != e1 && pe[e] > v2) { v2 = pe[e]; e2 = e; }
  if (lane == 0) {
    #pragma unroll
    for (int e = 0; e < E_NUM; ++e) probs_out[(size_t)t*E_NUM + e] = pe[e] * inv;
    topi[t*2+0] = e1; topw[t*2+0] = v1 * inv;
    topi[t*2+1] = e2; topw[t*2+1] = v2 * inv;
    atomicAdd(&counts[e1], 1);
    atomicAdd(&counts[e2], 1);
  }
}

// scan: 256-padded per-expert bases + tile->expert map (one block)
__global__ __launch_bounds__(256) void k_scan(
    const int* __restrict__ counts, int* __restrict__ pbase,
    int* __restrict__ tile_e)
{
  __shared__ int base_s[E_NUM + 1];
  const int tid = threadIdx.x;
  if (tid == 0) {
    int base = 0;
    #pragma unroll
    for (int e = 0; e < E_NUM; ++e) {
      base_s[e] = base;
      base += ((counts[e] + 255) >> 8) << 8;
    }
    base_s[E_NUM] = base;
  }
  __syncthreads();
  if (tid <= E_NUM) pbase[tid] = base_s[tid];
  if (tid < N_TILES) {
    const int r0 = tid << 8;
    int e = -1;
    #pragma unroll
    for (int k = 0; k < E_NUM; ++k)
      if (r0 >= base_s[k] && r0 < base_s[k+1]) e = k;
    tile_e[tid] = e;
  }
}

__global__ __launch_bounds__(256) void k_assign(
    const int* __restrict__ topi, const float* __restrict__ topw,
    const int* __restrict__ pbase, int* __restrict__ cursor,
    int* __restrict__ rows_token, float* __restrict__ rows_w,
    int* __restrict__ pair_of)
{
  const int t = blockIdx.x * 256 + threadIdx.x;
  if (t < T_TOK) {
    #pragma unroll
    for (int k = 0; k < 2; ++k) {
      const int e = topi[t*2+k];
      const int slot = atomicAdd(&cursor[e], 1);
      const int pid = pbase[e] + slot;
      rows_token[pid] = t;
      rows_w[pid] = topw[t*2+k];
      pair_of[t*2+k] = pid;
    }
  }
}

// transpose + convert: per expert, in fp32 [R][C] -> out bf16 [C][R]
template<int R, int C>
__global__ __launch_bounds__(256) void k_tcvt(const float* __restrict__ in,
                                              unsigned short* __restrict__ out)
{
  const size_t eo = (size_t)blockIdx.z * R * C;
  const int r0 = blockIdx.y * 64, c0 = blockIdx.x * 64;
  __shared__ unsigned short ls[64][66];
  const int t = threadIdx.x;
  const int rr = t >> 4, cc = (t & 15) * 4;
  #pragma unroll
  for (int p = 0; p < 4; ++p) {
    const float4 v = *(const float4*)&in[eo + (size_t)(r0 + p*16 + rr)*C + c0 + cc];
    ls[p*16+rr][cc+0]=f2bf(v.x); ls[p*16+rr][cc+1]=f2bf(v.y);
    ls[p*16+rr][cc+2]=f2bf(v.z); ls[p*16+rr][cc+3]=f2bf(v.w);
  }
  __syncthreads();
  const int kc = (t & 7) * 8, nn0 = t >> 3;
  #pragma unroll
  for (int p = 0; p < 2; ++p) {
    const int nn = nn0 + p*32;
    ushort8v o;
    #pragma unroll
    for (int j = 0; j < 8; ++j) o[j] = ls[kc + j][nn];
    *(ushort8v*)&out[eo + (size_t)(c0 + nn)*R + r0 + kc] = o;
  }
}

// grouped bf16 MFMA GEMM: BM=256, BN=256, BK=64, 8 waves (2Mx4N),
// 2-buffer LDS (128KB), 4 phases/K-tile, vmcnt(4)/K-tile.
// Block mapping: 1D grid; XCD q = b&7 owns (all bxz) x (by in [q*5,q*5+5)),
// B-panel-major order -> A set (2.5MB) L2-resident, B-panel reused x5.
// EPI 1: relu(acc+bias) -> h.   EPI 2: (acc + (z==0)*bias)*rows_w -> ypart[z].
template<bool GATHER, int NDIM, int KFULL, int EPI>
__global__ __launch_bounds__(512, 2) void k_gemm(
    const unsigned short* __restrict__ A,
    const unsigned short* __restrict__ Bt,   // per-expert [NDIM][KFULL] bf16
    const float* __restrict__ bias,          // [E][NDIM]
    const int* __restrict__ tile_e,
    const int* __restrict__ rows_token,
    const float* __restrict__ rows_w,
    unsigned short* __restrict__ outp,
    int nbx, int nkt, int kch)
{
  // XCD 2D sub-grid mapping (dispatch round-robin b%8 -> XCD, perf-only)
  const int b = blockIdx.x;
  const int q = b & 7;
  const int s = b >> 3;
  const int bxz = s / BYG;
  const int by  = q * BYG + (s - bxz * BYG);
  const int bx  = bxz % nbx;
  const int z   = bxz / nbx;
  const int e = tile_e[by];
  if (e < 0) return;
  const int rt = by * 256;
  const int ntc = bx * 256;
  const int koff = z * kch;
  // buffer: rows 0-255 = A-tile (256x64), rows 256-511 = B-tile. 64KB each.
  __shared__ __align__(16) unsigned short LB[2][512 * 64];
  const int tid = threadIdx.x;
  const int lane = tid & 63;
  const int w = tid >> 6;
  // staging: wave w<4 -> A rows [w*64, w*64+64); w>=4 -> B same. 8 calls/wave
  // per K-tile, each call = 8 rows x 128B (lane -> row=lane>>3, chunk lane&7).
  // LDS dest linear; global chunk pre-swizzled g = (lane&7) ^ (row&7).
  const int lr = lane >> 3;
  const int g  = (lane & 7) ^ lr;
  const unsigned short* gp[8];
  unsigned lbase[8];
  if (w < 4) {
    #pragma unroll
    for (int i = 0; i < 8; ++i) {
      const int rl = w*64 + i*8 + lr;
      const int rowidx = GATHER ? rows_token[rt + rl] : (rt + rl);
      gp[i] = A + (size_t)rowidx * KFULL + koff + g*8;
      lbase[i] = (unsigned)((w*64 + i*8) * 64);
    }
  } else {
    const unsigned short* Be = Bt + (size_t)e * NDIM * KFULL;
    #pragma unroll
    for (int i = 0; i < 8; ++i) {
      const int rl = (w-4)*64 + i*8 + lr;
      gp[i] = Be + (size_t)(ntc + rl) * KFULL + koff + g*8;
      lbase[i] = (unsigned)((256 + (w-4)*64 + i*8) * 64);
    }
  }
  const int wr = w >> 2, wc = w & 3;       // 2M x 4N, wave tile 128x64
  const int cl = lane & 15, rgb = lane >> 4;
  const int sz = cl & 7;                   // read-side XOR (row&7 == cl&7)
  f32x4 acc[8][4] = {};

  #define STG4(tt, bb, c0)                                    \
    { const int _ko = (tt) * 64;                              \
      gload16(gp[c0+0] + _ko, &LB[bb][lbase[c0+0]]);          \
      gload16(gp[c0+1] + _ko, &LB[bb][lbase[c0+1]]);          \
      gload16(gp[c0+2] + _ko, &LB[bb][lbase[c0+2]]);          \
      gload16(gp[c0+3] + _ko, &LB[bb][lbase[c0+3]]); }
  #define STG2(tt, bb, c0)                                    \
    { const int _ko = (tt) * 64;                              \
      gload16(gp[c0+0] + _ko, &LB[bb][lbase[c0+0]]);          \
      gload16(gp[c0+1] + _ko, &LB[bb][lbase[c0+1]]); }
  #define LGK0  asm volatile("s_waitcnt lgkmcnt(0)" ::: "memory")
  #define BAR   __builtin_amdgcn_s_barrier()

  // prologue: tile0 fully (8 calls), tile1 first half (4); certify tile0
  STG4(0, 0, 0) STG4(0, 0, 4)
  STG4(1, 1, 0)
  asm volatile("s_waitcnt vmcnt(4)" ::: "memory");
  BAR;

  for (int t = 0; t < nkt; ++t) {
    const int bb = t & 1;
    const unsigned short* Sb = &LB[bb][0];
    short8v a[4][2], b[4][2];
    // ---- P1: read a[0-3]+b[0-1]; stage t+1 calls 4,5 -> buf bb^1; q1
    #pragma unroll
    for (int m = 0; m < 4; ++m) {
      a[m][0] = *(const short8v*)&Sb[(wr*128 + m*16 + cl)*64 + ((0*4+rgb)^sz)*8];
      a[m][1] = *(const short8v*)&Sb[(wr*128 + m*16 + cl)*64 + ((1*4+rgb)^sz)*8];
    }
    #pragma unroll
    for (int n = 0; n < 2; ++n) {
      b[n][0] = *(const short8v*)&Sb[(256 + wc*64 + n*16 + cl)*64 + ((0*4+rgb)^sz)*8];
      b[n][1] = *(const short8v*)&Sb[(256 + wc*64 + n*16 + cl)*64 + ((1*4+rgb)^sz)*8];
    }
    if (t + 1 < nkt) STG2(t+1, bb^1, 4)
    BAR; LGK0;
    __builtin_amdgcn_s_setprio(1);
    #pragma unroll
    for (int m = 0; m < 4; ++m)
      #pragma unroll
      for (int n = 0; n < 2; ++n) {
        acc[m][n] = __builtin_amdgcn_mfma_f32_16x16x32_bf16(a[m][0], b[n][0], acc[m][n], 0, 0, 0);
        acc[m][n] = __builtin_amdgcn_mfma_f32_16x16x32_bf16(a[m][1], b[n][1], acc[m][n], 0, 0, 0);
      }
    __builtin_amdgcn_s_setprio(0);
    BAR;
    // ---- P2: read b[2-3]; stage t+1 calls 6,7; q2
    #pragma unroll
    for (int n = 2; n < 4; ++n) {
      b[n][0] = *(const short8v*)&Sb[(256 + wc*64 + n*16 + cl)*64 + ((0*4+rgb)^sz)*8];
      b[n][1] = *(const short8v*)&Sb[(256 + wc*64 + n*16 + cl)*64 + ((1*4+rgb)^sz)*8];
    }
    if (t + 1 < nkt) STG2(t+1, bb^1, 6)
    BAR; LGK0;
    __builtin_amdgcn_s_setprio(1);
    #pragma unroll
    for (int m = 0; m < 4; ++m)
      #pragma unroll
      for (int n = 2; n < 4; ++n) {
        acc[m][n] = __builtin_amdgcn_mfma_f32_16x16x32_bf16(a[m][0], b[n][0], acc[m][n], 0, 0, 0);
        acc[m][n] = __builtin_amdgcn_mfma_f32_16x16x32_bf16(a[m][1], b[n][1], acc[m][n], 0, 0, 0);
      }
    __builtin_amdgcn_s_setprio(0);
    BAR;
    // ---- P3: read a[4-7] (reuse regs); q3 (no staging: buf bb still read)
    #pragma unroll
    for (int m = 0; m < 4; ++m) {
      a[m][0] = *(const short8v*)&Sb[(wr*128 + (m+4)*16 + cl)*64 + ((0*4+rgb)^sz)*8];
      a[m][1] = *(const short8v*)&Sb[(wr*128 + (m+4)*16 + cl)*64 + ((1*4+rgb)^sz)*8];
    }
    BAR; LGK0;
    __builtin_amdgcn_s_setprio(1);
    #pragma unroll
    for (int m = 0; m < 4; ++m)
      #pragma unroll
      for (int n = 0; n < 2; ++n) {
        acc[m+4][n] = __builtin_amdgcn_mfma_f32_16x16x32_bf16(a[m][0], b[n][0], acc[m+4][n], 0, 0, 0);
        acc[m+4][n] = __builtin_amdgcn_mfma_f32_16x16x32_bf16(a[m][1], b[n][1], acc[m+4][n], 0, 0, 0);
      }
    __builtin_amdgcn_s_setprio(0);
    BAR;
    // ---- P4: stage t+2 calls 0-3 -> buf bb (bb reads all retired); vmcnt; q4
    if (t + 2 < nkt) {
      STG4(t+2, bb, 0)
      asm volatile("s_waitcnt vmcnt(4)" ::: "memory");   // tile t+1 landed
    } else if (t + 1 < nkt) {
      asm volatile("s_waitcnt vmcnt(0)" ::: "memory");
    }
    BAR;
    __builtin_amdgcn_s_setprio(1);
    #pragma unroll
    for (int m = 0; m < 4; ++m)
      #pragma unroll
      for (int n = 2; n < 4; ++n) {
        acc[m+4][n] = __builtin_amdgcn_mfma_f32_16x16x32_bf16(a[m][0], b[n][0], acc[m+4][n], 0, 0, 0);
        acc[m+4][n] = __builtin_amdgcn_mfma_f32_16x16x32_bf16(a[m][1], b[n][1], acc[m+4][n], 0, 0, 0);
      }
    __builtin_amdgcn_s_setprio(0);
    BAR;
  }
  #undef STG4
  #undef STG2
  #undef LGK0
  #undef BAR

  // epilogue: C/D layout col = lane&15, row = (lane>>4)*4 + reg  [m89]
  // pack bf16 pairs across lane^1 -> dword stores from even lanes
  unsigned short* op = outp;
  if (EPI == 2) op += (size_t)z * CAP_ROWS * NDIM;
  const bool addb = (EPI == 1) || (z == 0);
  const size_t ebias = (size_t)e * NDIM;
  #pragma unroll
  for (int m = 0; m < 8; ++m) {
    const int row = rt + wr*128 + m*16 + rgb*4;
    float4 rw4 = make_float4(0,0,0,0);
    if (EPI == 2) rw4 = *(const float4*)&rows_w[row];
    #pragma unroll
    for (int n = 0; n < 4; ++n) {
      const int col = ntc + wc*64 + n*16 + cl;
      const float bv = addb ? bias[ebias + col] : 0.f;
      #pragma unroll
      for (int r = 0; r < 4; ++r) {
        float v = acc[m][n][r] + bv;
        if (EPI == 1) v = fmaxf(v, 0.f);
        else          v *= ((const float*)&rw4)[r];
        const unsigned short hb = f2bf(v);
        const unsigned short ob = (unsigned short)__shfl_xor((int)(unsigned)hb, 1);
        if ((lane & 1) == 0) {
          const unsigned pk = (unsigned)hb | ((unsigned)ob << 16);
          *(unsigned*)&op[(size_t)(row + r)*NDIM + col] = pk;
        }
      }
    }
  }
}

// out[t] = sum_k sum_s ypart[s][pair_k(t)]  (fixed order -> deterministic)
__global__ __launch_bounds__(256) void k_combine(
    const unsigned short* __restrict__ yp, const int* __restrict__ pair_of,
    float* __restrict__ out, int ksplit)
{
  const int gid = blockIdx.x * 256 + threadIdx.x;   // T*D/8 threads
  const int t = gid >> 7;
  const int c = (gid & 127) * 8;
  float o[8] = {0,0,0,0,0,0,0,0};
  #pragma unroll
  for (int k = 0; k < 2; ++k) {
    const int p = pair_of[t*2+k];
    for (int s = 0; s < ksplit; ++s) {
      const ushort8v v = *(const ushort8v*)&yp[((size_t)s*CAP_ROWS + p)*D_DIM + c];
      #pragma unroll
      for (int j = 0; j < 8; ++j) o[j] += bf2f(v[j]);
    }
  }
  float4 o0; o0.x=o[0]; o0.y=o[1]; o0.z=o[2]; o0.w=o[3];
  float4 o1; o1.x=o[4]; o1.y=o[5]; o1.z=o[6]; o1.w=o[7];
  *(float4*)&out[(size_t)t*D_DIM + c]     = o0;
  *(float4*)&out[(size_t)t*D_DIM + c + 4] = o1;
}

extern "C" void kernel_launch(void* const* d_in, const int* in_sizes, int n_in,
                              void* d_out, int out_size, void* d_ws, size_t ws_size,
                              hipStream_t stream)
{
  const float* x  = (const float*)d_in[0];
  const float* Wr = (const float*)d_in[1];
  const float* br = (const float*)d_in[2];
  const float* W1 = (const float*)d_in[3];
  const float* b1 = (const float*)d_in[4];
  const float* W2 = (const float*)d_in[5];
  const float* b2 = (const float*)d_in[6];
  (void)in_sizes; (void)n_in; (void)out_size;

  float* out   = (float*)d_out;
  float* probs = out + (size_t)T_TOK * D_DIM;

  char* w = (char*)d_ws;
  size_t off = 0;
  int*   counts     = (int*)(w + off); off += 256;
  int*   cursor     = (int*)(w + off); off += 256;
  int*   pbase      = (int*)(w + off); off += 512;
  int*   tile_e     = (int*)(w + off); off += 3072;
  int*   topi       = (int*)(w + off); off += (size_t)T_TOK*2*4;
  float* topw       = (float*)(w + off); off += (size_t)T_TOK*2*4;
  int*   pair_of    = (int*)(w + off); off += (size_t)T_TOK*2*4;
  int*   rows_token = (int*)(w + off); off += (size_t)CAP_ROWS*4;
  float* rows_w     = (float*)(w + off); off += (size_t)CAP_ROWS*4;
  off = (off + 255) & ~(size_t)255;
  unsigned short* xbf = (unsigned short*)(w + off); off += (size_t)T_TOK*D_DIM*2;
  unsigned short* Wt  = (unsigned short*)(w + off); off += (size_t)E_NUM*D_DIM*F_DIM*2;
  unsigned short* h   = (unsigned short*)(w + off); off += (size_t)CAP_ROWS*F_DIM*2;
  unsigned short* yp  = (unsigned short*)(w + off);
  // choose GEMM2 K-split by available workspace (deterministic per run)
  const size_t ypart_bytes = (size_t)CAP_ROWS * D_DIM * 2;
  int ksplit = 1;
  if (ws_size >= off + 4 * ypart_bytes) ksplit = 4;
  else if (ws_size >= off + 2 * ypart_bytes) ksplit = 2;
  const int kch2 = F_DIM / ksplit;
  const int nkt2 = kch2 / 64;

  k_init<<<(CAP_ROWS + 255) / 256, 256, 0, stream>>>(counts, cursor, rows_token, rows_w);
  k_router<<<T_TOK / 4, 256, 0, stream>>>(x, Wr, br, probs, topi, topw, counts, xbf);
  k_scan<<<1, 256, 0, stream>>>(counts, pbase, tile_e);
  k_assign<<<T_TOK / 256, 256, 0, stream>>>(topi, topw, pbase, cursor,
                                            rows_token, rows_w, pair_of);
  // W1 [E][D][F] -> Wt [E][F][D] bf16
  k_tcvt<D_DIM, F_DIM><<<dim3(F_DIM/64, D_DIM/64, E_NUM), 256, 0, stream>>>(W1, Wt);
  // GEMM1: 640 blocks = 16 bxz x 40 by, K=1024 (nkt=16)
  k_gemm<true, F_DIM, D_DIM, 1><<<(F_DIM/256)*N_TILES, 512, 0, stream>>>(
      xbf, Wt, b1, tile_e, rows_token, rows_w, h, F_DIM/256, D_DIM/64, D_DIM);
  // W2 [E][F][D] -> Wt [E][D][F] bf16 (overwrites W1t; stream-ordered)
  k_tcvt<F_DIM, D_DIM><<<dim3(D_DIM/64, F_DIM/64, E_NUM), 256, 0, stream>>>(W2, Wt);
  // GEMM2: (4*ksplit) bxz x 40 by, K split into ksplit chunks
  k_gemm<false, D_DIM, F_DIM, 2><<<(D_DIM/256)*N_TILES*ksplit, 512, 0, stream>>>(
      h, Wt, b2, tile_e, rows_token, rows_w, yp, D_DIM/256, nkt2, kch2);
  k_combine<<<T_TOK * D_DIM / 8 / 256, 256, 0, stream>>>(yp, pair_of, out, ksplit);
}